// Round 2
// baseline (1190.438 us; speedup 1.0000x reference)
//
#include <hip/hip_runtime.h>

// NeuronGemma3DecoderLayer on MI355X (gfx950).
// Inputs/outputs are f32 (per reference); internal compute bf16 MFMA.
// S=2048, HID=2560, NH=8, NKV=4, HD=256, INTER=10240, WIN=512.

using u16 = unsigned short;
using u32 = unsigned int;
using short8  = __attribute__((ext_vector_type(8))) short;   // 8 x bf16 (4 VGPRs)
using floatx4 = __attribute__((ext_vector_type(4))) float;   // MFMA accum

__device__ __forceinline__ float bf2f(u16 u) { return __uint_as_float(((u32)u) << 16); }
__device__ __forceinline__ u16 f2bf(float f) {
  u32 b = __float_as_uint(f);
  return (u16)((b + 0x7fffu + ((b >> 16) & 1u)) >> 16);   // RNE
}
__device__ __forceinline__ float ldf(const float* p) { return *p; }
__device__ __forceinline__ float ldf(const u16* p) { return bf2f(*p); }
__device__ __forceinline__ void stf(float* p, float v) { *p = v; }
__device__ __forceinline__ void stf(u16* p, float v) { *p = f2bf(v); }
__device__ __forceinline__ float gelu_tanh(float x) {
  float u = 0.7978845608028654f * (x + 0.044715f * x * x * x);
  return 0.5f * x * (1.f + tanhf(u));
}
__device__ __forceinline__ void async16(const u16* g, u16* l) {
  __builtin_amdgcn_global_load_lds((const __attribute__((address_space(1))) void*)g,
                                   (__attribute__((address_space(3))) void*)l, 16, 0, 0);
}
#define MFMA(a, b, c) __builtin_amdgcn_mfma_f32_16x16x32_bf16((a), (b), (c), 0, 0, 0)

// ---------------------------------------------------------------------------
// Transpose f32 -> bf16: dst[c][r] = (bf16)src[r][c].
// Grid (cols/128, rows/64), block (64,4).
// ---------------------------------------------------------------------------
__global__ __launch_bounds__(256) void transpose_f2b_k(const float* __restrict__ src,
                                                       u16* __restrict__ dst,
                                                       int ss, int ds) {
  __shared__ u16 tile[128][66];
  const int t  = threadIdx.y * 64 + threadIdx.x;
  const int r0 = blockIdx.y * 64;
  const int c0 = blockIdx.x * 128;
#pragma unroll
  for (int i = 0; i < 16; ++i) {
    int u = i * 256 + t;
    int r = u >> 6;            // 0..63
    int cu = u & 63;           // pair col
    float2 v = *(const float2*)(src + (size_t)(r0 + r) * ss + c0 + cu * 2);
    tile[cu * 2][r]     = f2bf(v.x);
    tile[cu * 2 + 1][r] = f2bf(v.y);
  }
  __syncthreads();
#pragma unroll
  for (int i = 0; i < 16; ++i) {
    int u = i * 256 + t;
    int c = u >> 5;            // 0..127
    int ru = u & 31;           // pair col in dst row
    u32 v = (u32)tile[c][ru * 2] | ((u32)tile[c][ru * 2 + 1] << 16);
    *(u32*)(dst + (size_t)(c0 + c) * ds + r0 + ru * 2) = v;
  }
}

// Transpose bf16 -> bf16 (for V).
__global__ __launch_bounds__(256) void transpose_b2b_k(const u16* __restrict__ src,
                                                       u16* __restrict__ dst,
                                                       int ss, int ds) {
  __shared__ u16 tile[128][66];
  const int t  = threadIdx.y * 64 + threadIdx.x;
  const int r0 = blockIdx.y * 64;
  const int c0 = blockIdx.x * 128;
#pragma unroll
  for (int i = 0; i < 16; ++i) {
    int u = i * 256 + t;
    int r = u >> 6;
    int cu = u & 63;
    u32 v = *(const u32*)(src + (size_t)(r0 + r) * ss + c0 + cu * 2);
    tile[cu * 2][r]     = (u16)v;
    tile[cu * 2 + 1][r] = (u16)(v >> 16);
  }
  __syncthreads();
#pragma unroll
  for (int i = 0; i < 16; ++i) {
    int u = i * 256 + t;
    int c = u >> 5;
    int ru = u & 31;
    u32 v = (u32)tile[c][ru * 2] | ((u32)tile[c][ru * 2 + 1] << 16);
    *(u32*)(dst + (size_t)(c0 + c) * ds + r0 + ru * 2) = v;
  }
}

// ---------------------------------------------------------------------------
// RMSNorm over 2560 cols (+optional f32 residual). One block (256 thr) per row.
// out = in * rsqrt(mean(in^2)+eps) * (1+w)  [+ res]
// ---------------------------------------------------------------------------
template <typename TI, typename TO, bool RES>
__global__ __launch_bounds__(256) void rmsnorm_k(const TI* __restrict__ in,
                                                 const float* __restrict__ w,
                                                 const float* __restrict__ res,
                                                 TO* __restrict__ out) {
  const int row = blockIdx.x, t = threadIdx.x;
  const TI* ip = in + (size_t)row * 2560;
  float v[10];
  float ss = 0.f;
#pragma unroll
  for (int i = 0; i < 10; ++i) {
    v[i] = ldf(ip + t + i * 256);
    ss += v[i] * v[i];
  }
#pragma unroll
  for (int o = 32; o; o >>= 1) ss += __shfl_xor(ss, o, 64);
  __shared__ float ws4[4];
  if ((t & 63) == 0) ws4[t >> 6] = ss;
  __syncthreads();
  ss = (ws4[0] + ws4[1] + ws4[2] + ws4[3]) * (1.f / 2560.f);
  const float inv = rsqrtf(ss + 1e-6f);
#pragma unroll
  for (int i = 0; i < 10; ++i) {
    int c = t + i * 256;
    float o = v[i] * inv * (1.f + w[c]);
    if (RES) o += res[(size_t)row * 2560 + c];
    stf(out + (size_t)row * 2560 + c, o);
  }
}

// ---------------------------------------------------------------------------
// Per-head QK RMSNorm (HD=256) + RoPE, in-place on packed bf16 QKV (2048x4096).
// Grid (12, 2048): j<8 -> Q head j, j>=8 -> K head j-8. Block = 256 (one/dim).
// ---------------------------------------------------------------------------
__global__ __launch_bounds__(256) void qkrope_k(u16* __restrict__ qkv,
                                                const float* __restrict__ qw,
                                                const float* __restrict__ kw,
                                                const int* __restrict__ pos) {
  const int s = blockIdx.y, j = blockIdx.x, d = threadIdx.x;
  const int col = (j < 8) ? j * 256 : 2048 + (j - 8) * 256;
  const float* w = (j < 8) ? qw : kw;
  u16* p = qkv + (size_t)s * 4096 + col;
  float x = bf2f(p[d]);
  float ss = x * x;
#pragma unroll
  for (int o = 32; o; o >>= 1) ss += __shfl_xor(ss, o, 64);
  __shared__ float ws4[4];
  __shared__ float nb[256];
  if ((d & 63) == 0) ws4[d >> 6] = ss;
  __syncthreads();
  ss = (ws4[0] + ws4[1] + ws4[2] + ws4[3]) * (1.f / 256.f);
  float n = x * rsqrtf(ss + 1e-6f) * (1.f + w[d]);
  nb[d] = n;
  __syncthreads();
  float partner = nb[d ^ 128];
  float rot = (d < 128) ? -partner : partner;
  // inv_freq = 10000^{-(d&127)/128} ; log2(10000)=13.2877123795...
  float ang = (float)pos[s] * exp2f((float)(d & 127) * (-13.287712379549449f / 128.f));
  float sn, cs;
  sincosf(ang, &sn, &cs);
  p[d] = f2bf(n * cs + rot * sn);
}

// ---------------------------------------------------------------------------
// bf16 GEMM (m97 recipe): C[M,N] = A[M,K] @ B^T   where B is stored N x K.
// 128x128 tile, BK=32, 4 waves, each wave 4x4 MFMA 16x16x32, global_load_lds w16.
// EPI==1: C = gelu_tanh(acc) * Up[row,col]   (GLU fusion for the gate GEMM)
// ---------------------------------------------------------------------------
template <int EPI>
__global__ __launch_bounds__(256, 2) void gemm_bt(const u16* __restrict__ A,
                                                  const u16* __restrict__ B,
                                                  u16* __restrict__ C,
                                                  const u16* __restrict__ Up,
                                                  int M, int N, int K) {
  __shared__ u16 lA[128 * 32];
  __shared__ u16 lB[128 * 32];
  const int t = threadIdx.x;
  const int wave = t >> 6, lane = t & 63;
  const int quad = lane >> 4, lq = lane & 15;
  const int wm = wave >> 1, wn = wave & 1;
  const int bm = blockIdx.y * 128, bn = blockIdx.x * 128;

  floatx4 acc[4][4];
#pragma unroll
  for (int i = 0; i < 4; ++i)
#pragma unroll
    for (int j = 0; j < 4; ++j) acc[i][j] = (floatx4){0.f, 0.f, 0.f, 0.f};

  const u16* ga = A + (size_t)(bm + (t >> 2)) * K + (t & 3) * 8;
  const u16* gb = B + (size_t)(bn + (t >> 2)) * K + (t & 3) * 8;
  u16* la = lA + t * 8;  // t*16 bytes
  u16* lb = lB + t * 8;
  const int halfs = 64 * K;

  for (int k0 = 0; k0 < K; k0 += 32) {
    async16(ga + k0, la);
    async16(ga + k0 + halfs, la + 2048);
    async16(gb + k0, lb);
    async16(gb + k0 + halfs, lb + 2048);
    __syncthreads();  // drains vmcnt(0): LDS tiles ready
    short8 af[4], bf[4];
#pragma unroll
    for (int i = 0; i < 4; ++i)
      af[i] = *(const short8*)(lA + (wm * 64 + i * 16 + lq) * 32 + quad * 8);
#pragma unroll
    for (int j = 0; j < 4; ++j)
      bf[j] = *(const short8*)(lB + (wn * 64 + j * 16 + lq) * 32 + quad * 8);
#pragma unroll
    for (int i = 0; i < 4; ++i)
#pragma unroll
      for (int j = 0; j < 4; ++j) acc[i][j] = MFMA(af[i], bf[j], acc[i][j]);
    __syncthreads();
  }
  // C/D layout: col = lane&15, row = quad*4 + reg   [m89/m91 verified]
#pragma unroll
  for (int i = 0; i < 4; ++i) {
    const int row = bm + wm * 64 + i * 16 + quad * 4;
#pragma unroll
    for (int j = 0; j < 4; ++j) {
      const int col = bn + wn * 64 + j * 16 + lq;
#pragma unroll
      for (int r = 0; r < 4; ++r) {
        float v = acc[i][j][r];
        size_t idx = (size_t)(row + r) * N + col;
        if (EPI == 1) v = gelu_tanh(v) * bf2f(Up[idx]);
        C[idx] = f2bf(v);
      }
    }
  }
}

// ---------------------------------------------------------------------------
// GQA sliding-window flash attention. Block = 4 waves; each wave owns a 16-query
// tile of one head. QK^T and PV via MFMA 16x16x32; P round-trips through LDS
// (C-layout -> A-layout). Online softmax with per-row (m,l) in registers.
// qkv: 2048 x 4096 packed [Q(2048)|K(1024)|V(1024)]; vT: (NKV*HD=1024) x 2048.
// ---------------------------------------------------------------------------
__global__ __launch_bounds__(256, 2) void attn_k(const u16* __restrict__ qkv,
                                                 const u16* __restrict__ vT,
                                                 u16* __restrict__ out) {
  __shared__ u16 pb[4][16 * 32];
  const int t = threadIdx.x;
  const int wave = t >> 6, lane = t & 63;
  const int quad = lane >> 4, lq = lane & 15;
  const int h = blockIdx.y, kvh = h >> 1;
  const int q0 = (blockIdx.x * 4 + wave) * 16;

  // Q fragments (A-operand: m = lane&15, k = quad*8 + j), held for whole loop
  short8 qf[8];
  {
    const u16* qb = qkv + (size_t)(q0 + lq) * 4096 + h * 256 + quad * 8;
#pragma unroll
    for (int kk = 0; kk < 8; ++kk) qf[kk] = *(const short8*)(qb + kk * 32);
  }
  floatx4 acc[16];
#pragma unroll
  for (int n = 0; n < 16; ++n) acc[n] = (floatx4){0.f, 0.f, 0.f, 0.f};
  float mrun[4] = {-1e30f, -1e30f, -1e30f, -1e30f};
  float lrun[4] = {0.f, 0.f, 0.f, 0.f};

  int kstart = q0 - (512 - 1);
  if (kstart < 0) kstart = 0;
  kstart &= ~31;
  const int kend = q0 + 15;
  const u16* kb = qkv + 2048 + (size_t)kvh * 256 + quad * 8;
  const u16* vb = vT + (size_t)(kvh * 256 + lq) * 2048 + quad * 8;
  u16* pw = pb[wave];

  for (int kt = kstart; kt <= kend; kt += 32) {
    // K fragments (B-operand: n = key = lane&15, k = dim = quad*8+j)
    short8 kf[16];
#pragma unroll
    for (int hlf = 0; hlf < 2; ++hlf)
#pragma unroll
      for (int kk = 0; kk < 8; ++kk)
        kf[hlf * 8 + kk] =
            *(const short8*)(kb + (size_t)(kt + hlf * 16 + lq) * 4096 + kk * 32);
    floatx4 s0 = (floatx4){0.f, 0.f, 0.f, 0.f};
    floatx4 s1 = s0;
#pragma unroll
    for (int kk = 0; kk < 8; ++kk) {
      s0 = MFMA(qf[kk], kf[kk], s0);
      s1 = MFMA(qf[kk], kf[8 + kk], s1);
    }
    // online softmax; lane holds rows q0+quad*4+r, cols kt+lq / kt+16+lq
#pragma unroll
    for (int r = 0; r < 4; ++r) {
      const int q = q0 + quad * 4 + r;
      const int k0i = kt + lq, k1i = k0i + 16;
      float sc0 = s0[r] * 0.0625f, sc1 = s1[r] * 0.0625f;
      const bool m0 = (k0i <= q) && (q - k0i < 512);
      const bool m1 = (k1i <= q) && (q - k1i < 512);
      sc0 = m0 ? sc0 : -1e30f;
      sc1 = m1 ? sc1 : -1e30f;
      float mx = fmaxf(sc0, sc1);
#pragma unroll
      for (int o = 8; o; o >>= 1) mx = fmaxf(mx, __shfl_xor(mx, o, 64));
      const float mn = fmaxf(mrun[r], mx);
      const float al = __expf(mrun[r] - mn);
      const float p0 = m0 ? __expf(sc0 - mn) : 0.f;
      const float p1 = m1 ? __expf(sc1 - mn) : 0.f;
      float rs = p0 + p1;
#pragma unroll
      for (int o = 8; o; o >>= 1) rs += __shfl_xor(rs, o, 64);
      lrun[r] = lrun[r] * al + rs;
      mrun[r] = mn;
#pragma unroll
      for (int n = 0; n < 16; ++n) acc[n][r] *= al;
      pw[(quad * 4 + r) * 32 + lq] = f2bf(p0);
      pw[(quad * 4 + r) * 32 + 16 + lq] = f2bf(p1);
    }
    // wave-local LDS visibility (cannot __syncthreads: waves have different trip counts)
    __asm__ volatile("s_waitcnt lgkmcnt(0)" ::: "memory");
    const short8 pa = *(const short8*)(pw + lq * 32 + quad * 8);  // A-layout P
#pragma unroll
    for (int n = 0; n < 16; ++n) {
      const short8 vf = *(const short8*)(vb + (size_t)(n * 16) * 2048 + kt);
      acc[n] = MFMA(pa, vf, acc[n]);
    }
  }
#pragma unroll
  for (int n = 0; n < 16; ++n)
#pragma unroll
    for (int r = 0; r < 4; ++r) {
      const int q = q0 + quad * 4 + r;
      out[(size_t)q * 2048 + h * 256 + n * 16 + lq] = f2bf(acc[n][r] / lrun[r]);
    }
}

// ---------------------------------------------------------------------------
extern "C" void kernel_launch(void* const* d_in, const int* in_sizes, int n_in,
                              void* d_out, int out_size, void* d_ws, size_t ws_size,
                              hipStream_t stream) {
  (void)in_sizes; (void)n_in; (void)out_size; (void)ws_size;
  const float* x    = (const float*)d_in[0];
  const int*   pos  = (const int*)d_in[1];
  const float* wq   = (const float*)d_in[2];
  const float* wk   = (const float*)d_in[3];
  const float* wv   = (const float*)d_in[4];
  const float* wo   = (const float*)d_in[5];
  const float* qlw  = (const float*)d_in[6];
  const float* klw  = (const float*)d_in[7];
  const float* inln = (const float*)d_in[8];
  const float* paln = (const float*)d_in[9];
  const float* pfln = (const float*)d_in[10];
  const float* poln = (const float*)d_in[11];
  const float* wg   = (const float*)d_in[12];
  const float* wu   = (const float*)d_in[13];
  const float* wd   = (const float*)d_in[14];

  // workspace layout (u16 units); total 135,266,304 u16 = 258 MB
  u16* ws    = (u16*)d_ws;
  u16* qkvT  = ws;                     // 4096 x 2560 bf16   (later: x2 f32, same bytes)
  u16* woT   = qkvT + 10485760;        // 2560 x 2048        (later: 'down')
  u16* wgT   = woT + 5242880;          // 10240 x 2560
  u16* wuT   = wgT + 26214400;         // 10240 x 2560       (later: 'mid')
  u16* wdT   = wuT + 26214400;         // 2560 x 10240
  u16* h1    = wdT + 26214400;         // 2048 x 2560        (later: O-proj out)
  u16* qkv   = h1 + 5242880;           // 2048 x 4096        (later: 'h2')
  u16* vT    = qkv + 8388608;          // 1024 x 2048
  u16* attno = vT + 2097152;           // 2048 x 2048
  u16* up    = attno + 4194304;        // 2048 x 10240
  float* x2  = (float*)qkvT;           // 2048 x 2560 f32 (after step 2 frees qkvT)
  u16* h2    = qkv;                    // 2048 x 2560 bf16 (after step 5 frees qkv)

  const dim3 tb(64, 4);
  // weight transposes + bf16 cast (K-major -> N-major for MFMA B^T operand)
  transpose_f2b_k<<<dim3(2048 / 128, 2560 / 64), tb, 0, stream>>>(wq, qkvT, 2048, 2560);
  transpose_f2b_k<<<dim3(1024 / 128, 2560 / 64), tb, 0, stream>>>(wk, qkvT + (size_t)2048 * 2560, 1024, 2560);
  transpose_f2b_k<<<dim3(1024 / 128, 2560 / 64), tb, 0, stream>>>(wv, qkvT + (size_t)3072 * 2560, 1024, 2560);
  transpose_f2b_k<<<dim3(2560 / 128, 2048 / 64), tb, 0, stream>>>(wo, woT, 2560, 2048);
  transpose_f2b_k<<<dim3(10240 / 128, 2560 / 64), tb, 0, stream>>>(wg, wgT, 10240, 2560);
  transpose_f2b_k<<<dim3(10240 / 128, 2560 / 64), tb, 0, stream>>>(wu, wuT, 10240, 2560);
  transpose_f2b_k<<<dim3(2560 / 128, 10240 / 64), tb, 0, stream>>>(wd, wdT, 2560, 10240);

  // 1) input rmsnorm (f32 -> bf16)
  rmsnorm_k<float, u16, false><<<2048, 256, 0, stream>>>(x, inln, nullptr, h1);
  // 2) fused QKV projection: (2048x2560) @ (2560x4096)
  gemm_bt<0><<<dim3(4096 / 128, 2048 / 128), 256, 0, stream>>>(h1, qkvT, qkv, nullptr, 2048, 4096, 2560);
  // 3) per-head q/k rmsnorm + rope (in place)
  qkrope_k<<<dim3(12, 2048), 256, 0, stream>>>(qkv, qlw, klw, pos);
  // 4) V transpose for PV B-operand
  transpose_b2b_k<<<dim3(1024 / 128, 2048 / 64), tb, 0, stream>>>(qkv + 3072, vT, 4096, 2048);
  // 5) attention
  attn_k<<<dim3(2048 / 64, 8), 256, 0, stream>>>(qkv, vT, attno);
  // 6) O projection -> h1 (reuse)
  gemm_bt<0><<<dim3(2560 / 128, 2048 / 128), 256, 0, stream>>>(attno, woT, h1, nullptr, 2048, 2560, 2048);
  // 7) x2 = x + rmsnorm(o, post_attn)   (bf16 in, f32 out into freed qkvT)
  rmsnorm_k<u16, float, true><<<2048, 256, 0, stream>>>(h1, paln, x, x2);
  // 8) h2 = rmsnorm(x2, pre_ff)         (f32 -> bf16, into freed qkv)
  rmsnorm_k<float, u16, false><<<2048, 256, 0, stream>>>(x2, pfln, nullptr, h2);
  // 9) up = h2 @ w_up
  gemm_bt<0><<<dim3(10240 / 128, 2048 / 128), 256, 0, stream>>>(h2, wuT, up, nullptr, 2048, 10240, 2560);
  // 10) mid = gelu(h2 @ w_gate) * up    -> wuT buffer (reuse)
  gemm_bt<1><<<dim3(10240 / 128, 2048 / 128), 256, 0, stream>>>(h2, wgT, wuT, up, 2048, 10240, 2560);
  // 11) down = mid @ w_down             -> woT buffer (reuse)
  gemm_bt<0><<<dim3(2560 / 128, 2048 / 128), 256, 0, stream>>>(wuT, wdT, woT, nullptr, 2048, 2560, 10240);
  // 12) out = x2 + rmsnorm(down, post_ff)  (f32 out)
  rmsnorm_k<u16, float, true><<<2048, 256, 0, stream>>>(woT, poln, x2, (float*)d_out);
}

// Round 3
// 1155.883 us; speedup vs baseline: 1.0299x; 1.0299x over previous
//
#include <hip/hip_runtime.h>

// NeuronGemma3DecoderLayer on MI355X (gfx950).
// Inputs/outputs are f32 (per reference); internal compute bf16 MFMA.
// S=2048, HID=2560, NH=8, NKV=4, HD=256, INTER=10240, WIN=512.

using u16 = unsigned short;
using u32 = unsigned int;
using short8  = __attribute__((ext_vector_type(8))) short;   // 8 x bf16 (4 VGPRs)
using floatx4 = __attribute__((ext_vector_type(4))) float;   // MFMA accum

__device__ __forceinline__ float bf2f(u16 u) { return __uint_as_float(((u32)u) << 16); }
__device__ __forceinline__ u16 f2bf(float f) {
  u32 b = __float_as_uint(f);
  return (u16)((b + 0x7fffu + ((b >> 16) & 1u)) >> 16);   // RNE
}
__device__ __forceinline__ float ldf(const float* p) { return *p; }
__device__ __forceinline__ float ldf(const u16* p) { return bf2f(*p); }
__device__ __forceinline__ void stf(float* p, float v) { *p = v; }
__device__ __forceinline__ void stf(u16* p, float v) { *p = f2bf(v); }
__device__ __forceinline__ float gelu_tanh(float x) {
  // tanh-approx gelu with exp-based tanh (libm tanhf is slow-path).
  float u = 0.7978845608028654f * (x + 0.044715f * x * x * x);
  float t = __expf(2.f * u);                 // overflow->inf -> tanh->1 ok
  float th = 1.f - 2.f / (t + 1.f);
  return 0.5f * x * (1.f + th);
}
__device__ __forceinline__ void async16(const u16* g, u16* l) {
  __builtin_amdgcn_global_load_lds((const __attribute__((address_space(1))) void*)g,
                                   (__attribute__((address_space(3))) void*)l, 16, 0, 0);
}
#define MFMA(a, b, c) __builtin_amdgcn_mfma_f32_16x16x32_bf16((a), (b), (c), 0, 0, 0)

// ---------------------------------------------------------------------------
// Transpose f32 -> bf16: dst[c][r] = (bf16)src[r][c].
// Grid (cols/128, rows/64), block (64,4).
// ---------------------------------------------------------------------------
__global__ __launch_bounds__(256) void transpose_f2b_k(const float* __restrict__ src,
                                                       u16* __restrict__ dst,
                                                       int ss, int ds) {
  __shared__ u16 tile[128][66];
  const int t  = threadIdx.y * 64 + threadIdx.x;
  const int r0 = blockIdx.y * 64;
  const int c0 = blockIdx.x * 128;
#pragma unroll
  for (int i = 0; i < 16; ++i) {
    int u = i * 256 + t;
    int r = u >> 6;            // 0..63
    int cu = u & 63;           // pair col
    float2 v = *(const float2*)(src + (size_t)(r0 + r) * ss + c0 + cu * 2);
    tile[cu * 2][r]     = f2bf(v.x);
    tile[cu * 2 + 1][r] = f2bf(v.y);
  }
  __syncthreads();
#pragma unroll
  for (int i = 0; i < 16; ++i) {
    int u = i * 256 + t;
    int c = u >> 5;            // 0..127
    int ru = u & 31;           // pair col in dst row
    u32 v = (u32)tile[c][ru * 2] | ((u32)tile[c][ru * 2 + 1] << 16);
    *(u32*)(dst + (size_t)(c0 + c) * ds + r0 + ru * 2) = v;
  }
}

// Transpose bf16 -> bf16 (for V).
__global__ __launch_bounds__(256) void transpose_b2b_k(const u16* __restrict__ src,
                                                       u16* __restrict__ dst,
                                                       int ss, int ds) {
  __shared__ u16 tile[128][66];
  const int t  = threadIdx.y * 64 + threadIdx.x;
  const int r0 = blockIdx.y * 64;
  const int c0 = blockIdx.x * 128;
#pragma unroll
  for (int i = 0; i < 16; ++i) {
    int u = i * 256 + t;
    int r = u >> 6;
    int cu = u & 63;
    u32 v = *(const u32*)(src + (size_t)(r0 + r) * ss + c0 + cu * 2);
    tile[cu * 2][r]     = (u16)v;
    tile[cu * 2 + 1][r] = (u16)(v >> 16);
  }
  __syncthreads();
#pragma unroll
  for (int i = 0; i < 16; ++i) {
    int u = i * 256 + t;
    int c = u >> 5;
    int ru = u & 31;
    u32 v = (u32)tile[c][ru * 2] | ((u32)tile[c][ru * 2 + 1] << 16);
    *(u32*)(dst + (size_t)(c0 + c) * ds + r0 + ru * 2) = v;
  }
}

// ---------------------------------------------------------------------------
// RMSNorm over 2560 cols (+optional f32 residual). One block (256 thr) per row.
// ---------------------------------------------------------------------------
template <typename TI, typename TO, bool RES>
__global__ __launch_bounds__(256) void rmsnorm_k(const TI* __restrict__ in,
                                                 const float* __restrict__ w,
                                                 const float* __restrict__ res,
                                                 TO* __restrict__ out) {
  const int row = blockIdx.x, t = threadIdx.x;
  const TI* ip = in + (size_t)row * 2560;
  float v[10];
  float ss = 0.f;
#pragma unroll
  for (int i = 0; i < 10; ++i) {
    v[i] = ldf(ip + t + i * 256);
    ss += v[i] * v[i];
  }
#pragma unroll
  for (int o = 32; o; o >>= 1) ss += __shfl_xor(ss, o, 64);
  __shared__ float ws4[4];
  if ((t & 63) == 0) ws4[t >> 6] = ss;
  __syncthreads();
  ss = (ws4[0] + ws4[1] + ws4[2] + ws4[3]) * (1.f / 2560.f);
  const float inv = rsqrtf(ss + 1e-6f);
#pragma unroll
  for (int i = 0; i < 10; ++i) {
    int c = t + i * 256;
    float o = v[i] * inv * (1.f + w[c]);
    if (RES) o += res[(size_t)row * 2560 + c];
    stf(out + (size_t)row * 2560 + c, o);
  }
}

// ---------------------------------------------------------------------------
// Per-head QK RMSNorm (HD=256) + RoPE, in-place on packed bf16 QKV (2048x4096).
// ---------------------------------------------------------------------------
__global__ __launch_bounds__(256) void qkrope_k(u16* __restrict__ qkv,
                                                const float* __restrict__ qw,
                                                const float* __restrict__ kw,
                                                const int* __restrict__ pos) {
  const int s = blockIdx.y, j = blockIdx.x, d = threadIdx.x;
  const int col = (j < 8) ? j * 256 : 2048 + (j - 8) * 256;
  const float* w = (j < 8) ? qw : kw;
  u16* p = qkv + (size_t)s * 4096 + col;
  float x = bf2f(p[d]);
  float ss = x * x;
#pragma unroll
  for (int o = 32; o; o >>= 1) ss += __shfl_xor(ss, o, 64);
  __shared__ float ws4[4];
  __shared__ float nb[256];
  if ((d & 63) == 0) ws4[d >> 6] = ss;
  __syncthreads();
  ss = (ws4[0] + ws4[1] + ws4[2] + ws4[3]) * (1.f / 256.f);
  float n = x * rsqrtf(ss + 1e-6f) * (1.f + w[d]);
  nb[d] = n;
  __syncthreads();
  float partner = nb[d ^ 128];
  float rot = (d < 128) ? -partner : partner;
  float ang = (float)pos[s] * exp2f((float)(d & 127) * (-13.287712379549449f / 128.f));
  float sn, cs;
  sincosf(ang, &sn, &cs);
  p[d] = f2bf(n * cs + rot * sn);
}

// ---------------------------------------------------------------------------
// bf16 GEMM: C[M,N] = A[M,K] @ B^T (B stored N x K).  128x128 tile, BK=32,
// 4 waves x (4x4) MFMA 16x16x32, global_load_lds w16.
// DOUBLE-BUFFERED K-loop: one barrier per iter; loads for tile i+1 are issued
// right after the barrier and have the whole tile-i compute in flight before
// the next barrier's vmcnt(0) drain. (R2: single-buffer was latency-bound —
// MfmaUtil 18%, occupancy ~1.2 blk/CU.)  launch_bounds(256,3): >=3 blk/CU.
// EPI==1: C = gelu_tanh(acc) * Up[row,col]
// ---------------------------------------------------------------------------
template <int EPI>
__global__ __launch_bounds__(256, 3) void gemm_bt(const u16* __restrict__ A,
                                                  const u16* __restrict__ B,
                                                  u16* __restrict__ C,
                                                  const u16* __restrict__ Up,
                                                  int M, int N, int K) {
  __shared__ u16 lA[2][128 * 32];
  __shared__ u16 lB[2][128 * 32];
  const int t = threadIdx.x;
  const int wave = t >> 6, lane = t & 63;
  const int quad = lane >> 4, lq = lane & 15;
  const int wm = wave >> 1, wn = wave & 1;
  const int bm = blockIdx.y * 128, bn = blockIdx.x * 128;

  floatx4 acc[4][4];
#pragma unroll
  for (int i = 0; i < 4; ++i)
#pragma unroll
    for (int j = 0; j < 4; ++j) acc[i][j] = (floatx4){0.f, 0.f, 0.f, 0.f};

  const u16* ga = A + (size_t)(bm + (t >> 2)) * K + (t & 3) * 8;
  const u16* gb = B + (size_t)(bn + (t >> 2)) * K + (t & 3) * 8;
  const int halfs = 64 * K;
  const int toff = t * 8;  // t*16 bytes into each LDS tile

  // preload tile 0 -> buf 0
  async16(ga, lA[0] + toff);
  async16(ga + halfs, lA[0] + 2048 + toff);
  async16(gb, lB[0] + toff);
  async16(gb + halfs, lB[0] + 2048 + toff);

  const int niter = K >> 5;
  for (int i = 0; i < niter; ++i) {
    __syncthreads();  // drains vmcnt(0): buf[i&1] ready; all waves done reading buf[(i+1)&1]
    if (i + 1 < niter) {
      const int k0 = (i + 1) << 5;
      u16* lan = lA[(i + 1) & 1];
      u16* lbn = lB[(i + 1) & 1];
      async16(ga + k0, lan + toff);
      async16(ga + k0 + halfs, lan + 2048 + toff);
      async16(gb + k0, lbn + toff);
      async16(gb + k0 + halfs, lbn + 2048 + toff);
    }
    const u16* la = lA[i & 1];
    const u16* lb = lB[i & 1];
    short8 af[4], bf[4];
#pragma unroll
    for (int ii = 0; ii < 4; ++ii)
      af[ii] = *(const short8*)(la + (wm * 64 + ii * 16 + lq) * 32 + quad * 8);
#pragma unroll
    for (int j = 0; j < 4; ++j)
      bf[j] = *(const short8*)(lb + (wn * 64 + j * 16 + lq) * 32 + quad * 8);
#pragma unroll
    for (int ii = 0; ii < 4; ++ii)
#pragma unroll
      for (int j = 0; j < 4; ++j) acc[ii][j] = MFMA(af[ii], bf[j], acc[ii][j]);
  }
  // C/D layout: col = lane&15, row = quad*4 + reg   [m89/m91 verified]
#pragma unroll
  for (int i = 0; i < 4; ++i) {
    const int row = bm + wm * 64 + i * 16 + quad * 4;
#pragma unroll
    for (int j = 0; j < 4; ++j) {
      const int col = bn + wn * 64 + j * 16 + lq;
#pragma unroll
      for (int r = 0; r < 4; ++r) {
        float v = acc[i][j][r];
        size_t idx = (size_t)(row + r) * N + col;
        if (EPI == 1) v = gelu_tanh(v) * bf2f(Up[idx]);
        C[idx] = f2bf(v);
      }
    }
  }
}

// ---------------------------------------------------------------------------
// GQA sliding-window flash attention (unchanged from R2; not in top dispatches).
// ---------------------------------------------------------------------------
__global__ __launch_bounds__(256, 2) void attn_k(const u16* __restrict__ qkv,
                                                 const u16* __restrict__ vT,
                                                 u16* __restrict__ out) {
  __shared__ u16 pb[4][16 * 32];
  const int t = threadIdx.x;
  const int wave = t >> 6, lane = t & 63;
  const int quad = lane >> 4, lq = lane & 15;
  const int h = blockIdx.y, kvh = h >> 1;
  const int q0 = (blockIdx.x * 4 + wave) * 16;

  short8 qf[8];
  {
    const u16* qb = qkv + (size_t)(q0 + lq) * 4096 + h * 256 + quad * 8;
#pragma unroll
    for (int kk = 0; kk < 8; ++kk) qf[kk] = *(const short8*)(qb + kk * 32);
  }
  floatx4 acc[16];
#pragma unroll
  for (int n = 0; n < 16; ++n) acc[n] = (floatx4){0.f, 0.f, 0.f, 0.f};
  float mrun[4] = {-1e30f, -1e30f, -1e30f, -1e30f};
  float lrun[4] = {0.f, 0.f, 0.f, 0.f};

  int kstart = q0 - (512 - 1);
  if (kstart < 0) kstart = 0;
  kstart &= ~31;
  const int kend = q0 + 15;
  const u16* kb = qkv + 2048 + (size_t)kvh * 256 + quad * 8;
  const u16* vb = vT + (size_t)(kvh * 256 + lq) * 2048 + quad * 8;
  u16* pw = pb[wave];

  for (int kt = kstart; kt <= kend; kt += 32) {
    short8 kf[16];
#pragma unroll
    for (int hlf = 0; hlf < 2; ++hlf)
#pragma unroll
      for (int kk = 0; kk < 8; ++kk)
        kf[hlf * 8 + kk] =
            *(const short8*)(kb + (size_t)(kt + hlf * 16 + lq) * 4096 + kk * 32);
    floatx4 s0 = (floatx4){0.f, 0.f, 0.f, 0.f};
    floatx4 s1 = s0;
#pragma unroll
    for (int kk = 0; kk < 8; ++kk) {
      s0 = MFMA(qf[kk], kf[kk], s0);
      s1 = MFMA(qf[kk], kf[8 + kk], s1);
    }
#pragma unroll
    for (int r = 0; r < 4; ++r) {
      const int q = q0 + quad * 4 + r;
      const int k0i = kt + lq, k1i = k0i + 16;
      float sc0 = s0[r] * 0.0625f, sc1 = s1[r] * 0.0625f;
      const bool m0 = (k0i <= q) && (q - k0i < 512);
      const bool m1 = (k1i <= q) && (q - k1i < 512);
      sc0 = m0 ? sc0 : -1e30f;
      sc1 = m1 ? sc1 : -1e30f;
      float mx = fmaxf(sc0, sc1);
#pragma unroll
      for (int o = 8; o; o >>= 1) mx = fmaxf(mx, __shfl_xor(mx, o, 64));
      const float mn = fmaxf(mrun[r], mx);
      const float al = __expf(mrun[r] - mn);
      const float p0 = m0 ? __expf(sc0 - mn) : 0.f;
      const float p1 = m1 ? __expf(sc1 - mn) : 0.f;
      float rs = p0 + p1;
#pragma unroll
      for (int o = 8; o; o >>= 1) rs += __shfl_xor(rs, o, 64);
      lrun[r] = lrun[r] * al + rs;
      mrun[r] = mn;
#pragma unroll
      for (int n = 0; n < 16; ++n) acc[n][r] *= al;
      pw[(quad * 4 + r) * 32 + lq] = f2bf(p0);
      pw[(quad * 4 + r) * 32 + 16 + lq] = f2bf(p1);
    }
    __asm__ volatile("s_waitcnt lgkmcnt(0)" ::: "memory");
    const short8 pa = *(const short8*)(pw + lq * 32 + quad * 8);
#pragma unroll
    for (int n = 0; n < 16; ++n) {
      const short8 vf = *(const short8*)(vb + (size_t)(n * 16) * 2048 + kt);
      acc[n] = MFMA(pa, vf, acc[n]);
    }
  }
#pragma unroll
  for (int n = 0; n < 16; ++n)
#pragma unroll
    for (int r = 0; r < 4; ++r) {
      const int q = q0 + quad * 4 + r;
      out[(size_t)q * 2048 + h * 256 + n * 16 + lq] = f2bf(acc[n][r] / lrun[r]);
    }
}

// ---------------------------------------------------------------------------
extern "C" void kernel_launch(void* const* d_in, const int* in_sizes, int n_in,
                              void* d_out, int out_size, void* d_ws, size_t ws_size,
                              hipStream_t stream) {
  (void)in_sizes; (void)n_in; (void)out_size; (void)ws_size;
  const float* x    = (const float*)d_in[0];
  const int*   pos  = (const int*)d_in[1];
  const float* wq   = (const float*)d_in[2];
  const float* wk   = (const float*)d_in[3];
  const float* wv   = (const float*)d_in[4];
  const float* wo   = (const float*)d_in[5];
  const float* qlw  = (const float*)d_in[6];
  const float* klw  = (const float*)d_in[7];
  const float* inln = (const float*)d_in[8];
  const float* paln = (const float*)d_in[9];
  const float* pfln = (const float*)d_in[10];
  const float* poln = (const float*)d_in[11];
  const float* wg   = (const float*)d_in[12];
  const float* wu   = (const float*)d_in[13];
  const float* wd   = (const float*)d_in[14];

  // workspace layout (u16 units); total 135,266,304 u16 = 258 MB
  u16* ws    = (u16*)d_ws;
  u16* qkvT  = ws;                     // 4096 x 2560 bf16   (later: x2 f32, same bytes)
  u16* woT   = qkvT + 10485760;        // 2560 x 2048        (later: 'down')
  u16* wgT   = woT + 5242880;          // 10240 x 2560
  u16* wuT   = wgT + 26214400;         // 10240 x 2560       (later: 'mid')
  u16* wdT   = wuT + 26214400;         // 2560 x 10240
  u16* h1    = wdT + 26214400;         // 2048 x 2560        (later: O-proj out)
  u16* qkv   = h1 + 5242880;           // 2048 x 4096        (later: 'h2')
  u16* vT    = qkv + 8388608;          // 1024 x 2048
  u16* attno = vT + 2097152;           // 2048 x 2048
  u16* up    = attno + 4194304;        // 2048 x 10240
  float* x2  = (float*)qkvT;           // 2048 x 2560 f32 (after step 2 frees qkvT)
  u16* h2    = qkv;                    // 2048 x 2560 bf16 (after step 5 frees qkv)

  const dim3 tb(64, 4);
  transpose_f2b_k<<<dim3(2048 / 128, 2560 / 64), tb, 0, stream>>>(wq, qkvT, 2048, 2560);
  transpose_f2b_k<<<dim3(1024 / 128, 2560 / 64), tb, 0, stream>>>(wk, qkvT + (size_t)2048 * 2560, 1024, 2560);
  transpose_f2b_k<<<dim3(1024 / 128, 2560 / 64), tb, 0, stream>>>(wv, qkvT + (size_t)3072 * 2560, 1024, 2560);
  transpose_f2b_k<<<dim3(2560 / 128, 2048 / 64), tb, 0, stream>>>(wo, woT, 2560, 2048);
  transpose_f2b_k<<<dim3(10240 / 128, 2560 / 64), tb, 0, stream>>>(wg, wgT, 10240, 2560);
  transpose_f2b_k<<<dim3(10240 / 128, 2560 / 64), tb, 0, stream>>>(wu, wuT, 10240, 2560);
  transpose_f2b_k<<<dim3(2560 / 128, 10240 / 64), tb, 0, stream>>>(wd, wdT, 2560, 10240);

  // 1) input rmsnorm (f32 -> bf16)
  rmsnorm_k<float, u16, false><<<2048, 256, 0, stream>>>(x, inln, nullptr, h1);
  // 2) fused QKV projection
  gemm_bt<0><<<dim3(4096 / 128, 2048 / 128), 256, 0, stream>>>(h1, qkvT, qkv, nullptr, 2048, 4096, 2560);
  // 3) per-head q/k rmsnorm + rope (in place)
  qkrope_k<<<dim3(12, 2048), 256, 0, stream>>>(qkv, qlw, klw, pos);
  // 4) V transpose for PV B-operand
  transpose_b2b_k<<<dim3(1024 / 128, 2048 / 64), tb, 0, stream>>>(qkv + 3072, vT, 4096, 2048);
  // 5) attention
  attn_k<<<dim3(2048 / 64, 8), 256, 0, stream>>>(qkv, vT, attno);
  // 6) O projection -> h1 (reuse)
  gemm_bt<0><<<dim3(2560 / 128, 2048 / 128), 256, 0, stream>>>(attno, woT, h1, nullptr, 2048, 2560, 2048);
  // 7) x2 = x + rmsnorm(o, post_attn)
  rmsnorm_k<u16, float, true><<<2048, 256, 0, stream>>>(h1, paln, x, x2);
  // 8) h2 = rmsnorm(x2, pre_ff)
  rmsnorm_k<float, u16, false><<<2048, 256, 0, stream>>>(x2, pfln, nullptr, h2);
  // 9) up = h2 @ w_up
  gemm_bt<0><<<dim3(10240 / 128, 2048 / 128), 256, 0, stream>>>(h2, wuT, up, nullptr, 2048, 10240, 2560);
  // 10) mid = gelu(h2 @ w_gate) * up
  gemm_bt<1><<<dim3(10240 / 128, 2048 / 128), 256, 0, stream>>>(h2, wgT, wuT, up, 2048, 10240, 2560);
  // 11) down = mid @ w_down
  gemm_bt<0><<<dim3(2560 / 128, 2048 / 128), 256, 0, stream>>>(wuT, wdT, woT, nullptr, 2048, 2560, 10240);
  // 12) out = x2 + rmsnorm(down, post_ff)
  rmsnorm_k<u16, float, true><<<2048, 256, 0, stream>>>(woT, poln, x2, (float*)d_out);
}